// Round 1
// baseline (254.739 us; speedup 1.0000x reference)
//
#include <hip/hip_runtime.h>
#include <math.h>

#define NB 16
#define CIN 128
#define COUT 128
#define SDIM 512
#define HH 128
#define WW 128

typedef __bf16 bf16x8 __attribute__((ext_vector_type(8)));
typedef float f32x4 __attribute__((ext_vector_type(4)));

static constexpr size_t WA_OFF = 8192;                          // after s (2048 f32)
static constexpr size_t WA_ELEMS = (size_t)NB * 9 * COUT * CIN; // 2,359,296 bf16
static constexpr size_t XT_OFF = WA_OFF + WA_ELEMS * 2;         // 4,726,784
static constexpr size_t XT_ELEMS = (size_t)NB * 130 * 130 * CIN;
static constexpr size_t WS_NEEDED = XT_OFF + XT_ELEMS * 2;      // ~74 MB

__device__ __forceinline__ unsigned short f32_bf16(float f) {
  unsigned int x = __float_as_uint(f);
  x += 0x7fffu + ((x >> 16) & 1u);
  return (unsigned short)(x >> 16);
}

// ---------------- K0: s[b][cin] = style[b] . mod_w[cin] ----------------
__global__ void k_style(const float* __restrict__ style, const float* __restrict__ mod_w,
                        float* __restrict__ s) {
  int b = blockIdx.x, ci = threadIdx.x;
  const float4* st = (const float4*)(style + (size_t)b * SDIM);
  const float4* mw = (const float4*)(mod_w + (size_t)ci * SDIM);
  float acc = 0.f;
  for (int i = 0; i < SDIM / 4; ++i) {
    float4 a = st[i], m = mw[i];
    acc += a.x * m.x + a.y * m.y + a.z * m.z + a.w * m.w;
  }
  s[b * CIN + ci] = acc;
}

// ---------------- K1: demod + wA[b][tap][cout][cin] (bf16) ----------------
__global__ void k_wprep(const float* __restrict__ weight, const float* __restrict__ s,
                        unsigned short* __restrict__ wA) {
  int co = blockIdx.x, b = blockIdx.y, ci = threadIdx.x;
  const float scale = 0.029462782549439483f; // 1/sqrt(128*9)
  float sv = s[b * CIN + ci];
  const float* wp = weight + ((size_t)co * CIN + ci) * 9;
  float u[9], ss = 0.f;
#pragma unroll
  for (int t = 0; t < 9; ++t) { u[t] = scale * wp[t] * sv; ss += u[t] * u[t]; }
#pragma unroll
  for (int off = 32; off; off >>= 1) ss += __shfl_down(ss, off, 64);
  __shared__ float red[2];
  if ((threadIdx.x & 63) == 0) red[threadIdx.x >> 6] = ss;
  __syncthreads();
  float demod = rsqrtf(red[0] + red[1] + 1e-8f);
#pragma unroll
  for (int t = 0; t < 9; ++t)
    wA[((size_t)(b * 9 + t) * COUT + co) * CIN + ci] = f32_bf16(u[t] * demod);
}

// ---------------- K2: xt[b][h+1][w+1][cin] = bf16(x[b][cin][h][w]) ----------------
// border (y==0||y==129||x==0||x==129) stays zero from memset
__global__ void k_xt(const float* __restrict__ x, unsigned short* __restrict__ xt) {
  int h = blockIdx.x, b = blockIdx.y;
  int t = threadIdx.x;
  int cg = t & 15, w0 = t >> 4; // cin group (8 ch), w base
  const float* xp = x + ((size_t)(b * CIN + cg * 8) * HH + h) * WW;
  unsigned short* op = xt + ((size_t)b * 130 + (h + 1)) * 130 * CIN;
  for (int it = 0; it < 8; ++it) {
    int w = w0 + it * 16;
    uint4 pack;
    unsigned short* pu = (unsigned short*)&pack;
#pragma unroll
    for (int j = 0; j < 8; ++j) pu[j] = f32_bf16(xp[(size_t)j * HH * WW + w]);
    *(uint4*)(op + (size_t)(w + 1) * CIN + cg * 8) = pack;
  }
}

// ---------------- K3: conv via 9 shifted MFMA-GEMMs ----------------
// block: 256 thr = 4 waves (2 wm x 2 wn); tile = all 128 cout x 16x16 pixels
// wave: 4 m-subtiles (64 cout) x 8 n-subtiles (8 pixel rows)
__launch_bounds__(256)
__global__ void k_conv(const unsigned short* __restrict__ xt,
                       const unsigned short* __restrict__ wA,
                       const float* __restrict__ noise,
                       const float* __restrict__ nw,
                       float* __restrict__ out) {
  __shared__ uint4 lds[324 * 5]; // 18x18 cells, 80B each (64B data + 16B pad)
  int b = blockIdx.y;
  int tile = blockIdx.x;
  int th = (tile >> 3) * 16, tw = (tile & 7) * 16;
  int t = threadIdx.x;
  int lane = t & 63, wv = t >> 6;
  int wm = wv >> 1, wn = wv & 1;
  int lc = lane & 15, lg = lane >> 4;

  f32x4 acc[4][8];
#pragma unroll
  for (int mi = 0; mi < 4; ++mi)
#pragma unroll
    for (int j = 0; j < 8; ++j) acc[mi][j] = (f32x4){0.f, 0.f, 0.f, 0.f};

  const unsigned short* xtile = xt + ((size_t)b * 130 + th) * 130 * CIN + (size_t)tw * CIN;
  const unsigned short* wbase = wA + (size_t)b * 9 * COUT * CIN
                                + (size_t)(wm * 64 + lc) * CIN + lg * 8;

  for (int q = 0; q < 4; ++q) { // cin chunks of 32
    if (q) __syncthreads();
    // ---- stage 18x18x32 bf16 chunk into LDS (padded cells) ----
    const unsigned short* xq = xtile + q * 32;
#pragma unroll
    for (int i = 0; i < 6; ++i) {
      int idx = i * 256 + t;
      if (idx < 1296) {
        int cell = idx >> 2, g = idx & 3;
        int y = cell / 18, xx = cell - y * 18;
        uint4 v = *(const uint4*)(xq + ((size_t)y * 130 + xx) * CIN + g * 8);
        lds[cell * 5 + g] = v;
      }
    }
    __syncthreads();
    // ---- compute ----
    const unsigned short* wq = wbase + (size_t)q * 32;
#pragma unroll
    for (int ky = 0; ky < 3; ++ky) {
#pragma unroll
      for (int kx = 0; kx < 3; ++kx) {
        int tap = ky * 3 + kx;
        bf16x8 af[4];
#pragma unroll
        for (int mi = 0; mi < 4; ++mi)
          af[mi] = *(const bf16x8*)(wq + ((size_t)tap * COUT + mi * 16) * CIN);
#pragma unroll
        for (int j = 0; j < 8; ++j) {
          int bofs = ((wn * 8 + j + ky) * 18 + (lc + kx)) * 5 + lg;
          bf16x8 bv = *((const bf16x8*)lds + bofs);
#pragma unroll
          for (int mi = 0; mi < 4; ++mi)
            acc[mi][j] = __builtin_amdgcn_mfma_f32_16x16x32_bf16(af[mi], bv, acc[mi][j], 0, 0, 0);
        }
      }
    }
  }

  // ---- epilogue: + noise_weight[cout]*noise, store fp32 ----
#pragma unroll
  for (int mi = 0; mi < 4; ++mi) {
    int cobase = wm * 64 + mi * 16 + lg * 4;
    float nwv[4];
#pragma unroll
    for (int r = 0; r < 4; ++r) nwv[r] = nw[cobase + r];
#pragma unroll
    for (int j = 0; j < 8; ++j) {
      int hh = th + wn * 8 + j, ww = tw + lc;
      float nv = noise[((size_t)b * HH + hh) * WW + ww];
#pragma unroll
      for (int r = 0; r < 4; ++r)
        out[(((size_t)b * COUT + cobase + r) * HH + hh) * WW + ww] = acc[mi][j][r] + nwv[r] * nv;
    }
  }
}

extern "C" void kernel_launch(void* const* d_in, const int* in_sizes, int n_in,
                              void* d_out, int out_size, void* d_ws, size_t ws_size,
                              hipStream_t stream) {
  const float* x      = (const float*)d_in[0];
  const float* style  = (const float*)d_in[1];
  const float* noise  = (const float*)d_in[2];
  const float* weight = (const float*)d_in[3];
  const float* mod_w  = (const float*)d_in[4];
  const float* nw     = (const float*)d_in[5];
  float* out = (float*)d_out;
  char* ws = (char*)d_ws;
  if (ws_size < WS_NEEDED) return; // visible failure if scratch too small

  float* s = (float*)ws;
  unsigned short* wA = (unsigned short*)(ws + WA_OFF);
  unsigned short* xt = (unsigned short*)(ws + XT_OFF);

  hipMemsetAsync(xt, 0, XT_ELEMS * 2, stream); // zero halo (and interior, overwritten)
  k_style<<<dim3(NB), dim3(CIN), 0, stream>>>(style, mod_w, s);
  k_wprep<<<dim3(COUT, NB), dim3(CIN), 0, stream>>>(weight, s, wA);
  k_xt<<<dim3(HH, NB), dim3(256), 0, stream>>>(x, xt);
  k_conv<<<dim3(64, NB), dim3(256), 0, stream>>>(xt, wA, noise, nw, out);
}

// Round 2
// 167.687 us; speedup vs baseline: 1.5191x; 1.5191x over previous
//
#include <hip/hip_runtime.h>
#include <math.h>

#define NB 16
#define CIN 128
#define COUT 128
#define SDIM 512
#define HH 128
#define WW 128

typedef __bf16 bf16x8 __attribute__((ext_vector_type(8)));
typedef float f32x4 __attribute__((ext_vector_type(4)));

static constexpr size_t WA_OFF = 8192;                          // after s (2048 f32)
static constexpr size_t WA_ELEMS = (size_t)NB * 9 * COUT * CIN; // 2,359,296 bf16
static constexpr size_t XT_OFF = WA_OFF + WA_ELEMS * 2;
static constexpr size_t XT_ELEMS = (size_t)NB * 130 * 130 * CIN;
static constexpr size_t WS_NEEDED = XT_OFF + XT_ELEMS * 2;

__device__ __forceinline__ unsigned short f32_bf16(float f) {
  unsigned int x = __float_as_uint(f);
  x += 0x7fffu + ((x >> 16) & 1u);
  return (unsigned short)(x >> 16);
}

__device__ __forceinline__ void gl_lds16(const void* g, void* l) {
  __builtin_amdgcn_global_load_lds((const __attribute__((address_space(1))) void*)g,
                                   (__attribute__((address_space(3))) void*)l, 16, 0, 0);
}

// ---------------- K0: s[b][cin] = style[b] . mod_w[cin] ----------------
__global__ void k_style(const float* __restrict__ style, const float* __restrict__ mod_w,
                        float* __restrict__ s) {
  int b = blockIdx.x, ci = threadIdx.x;
  const float4* st = (const float4*)(style + (size_t)b * SDIM);
  const float4* mw = (const float4*)(mod_w + (size_t)ci * SDIM);
  float acc = 0.f;
  for (int i = 0; i < SDIM / 4; ++i) {
    float4 a = st[i], m = mw[i];
    acc += a.x * m.x + a.y * m.y + a.z * m.z + a.w * m.w;
  }
  s[b * CIN + ci] = acc;
}

// ---------------- K1: demod + wA[b][tap][cout][cin] (bf16) ----------------
__global__ void k_wprep(const float* __restrict__ weight, const float* __restrict__ s,
                        unsigned short* __restrict__ wA) {
  int co = blockIdx.x, b = blockIdx.y, ci = threadIdx.x;
  const float scale = 0.029462782549439483f; // 1/sqrt(128*9)
  float sv = s[b * CIN + ci];
  const float* wp = weight + ((size_t)co * CIN + ci) * 9;
  float u[9], ss = 0.f;
#pragma unroll
  for (int t = 0; t < 9; ++t) { u[t] = scale * wp[t] * sv; ss += u[t] * u[t]; }
#pragma unroll
  for (int off = 32; off; off >>= 1) ss += __shfl_down(ss, off, 64);
  __shared__ float red[2];
  if ((threadIdx.x & 63) == 0) red[threadIdx.x >> 6] = ss;
  __syncthreads();
  float demod = rsqrtf(red[0] + red[1] + 1e-8f);
#pragma unroll
  for (int t = 0; t < 9; ++t)
    wA[((size_t)(b * 9 + t) * COUT + co) * CIN + ci] = f32_bf16(u[t] * demod);
}

// ---------------- K2: xt[b][hb][wb][cin] transpose, halo written in-kernel ----
// grid (130, NB). hb==0/129 -> zero row. else transpose x row hb-1.
__global__ void k_xt(const float* __restrict__ x, unsigned short* __restrict__ xt) {
  int hb = blockIdx.x, b = blockIdx.y;
  int t = threadIdx.x;
  unsigned short* orow = xt + ((size_t)b * 130 + hb) * 130 * CIN;
  if (hb == 0 || hb == 129) {
    uint4 z = {0u, 0u, 0u, 0u};
    for (int u = t; u < 2080; u += 256) ((uint4*)orow)[u] = z;
    return;
  }
  __shared__ unsigned short lds[128][132]; // [w][c], stride 264B (8B-aligned rows)
  int h = hb - 1;
  const float* xrow = x + (size_t)b * CIN * HH * WW + (size_t)h * WW;
  // load (coalesced f32) + transpose into LDS
  for (int i = 0; i < 32; ++i) {
    int flat = i * 256 + t;
    int w = flat & 127, cp = flat >> 7; // cp: channel pair 0..63
    float a0 = xrow[(size_t)(2 * cp) * HH * WW + w];
    float a1 = xrow[(size_t)(2 * cp + 1) * HH * WW + w];
    unsigned int pk = (unsigned int)f32_bf16(a0) | ((unsigned int)f32_bf16(a1) << 16);
    *(unsigned int*)&lds[w][2 * cp] = pk;
  }
  __syncthreads();
  // zero halo cols 0 and 129
  if (t < 32) {
    int side = t >> 4, g = t & 15;
    uint4 z = {0u, 0u, 0u, 0u};
    ((uint4*)(orow + (side ? (size_t)129 * CIN : 0)))[g] = z;
  }
  // write interior cols 1..128 (c contiguous, coalesced uint4)
  for (int i = 0; i < 8; ++i) {
    int u = i * 256 + t;            // 0..2047
    int w = u >> 4, cg = u & 15;    // 8 channels per unit
    uint2 v0 = *(const uint2*)&lds[w][cg * 8];
    uint2 v1 = *(const uint2*)&lds[w][cg * 8 + 4];
    uint4 v = {v0.x, v0.y, v1.x, v1.y};
    *(uint4*)(orow + (size_t)(1 + w) * CIN + cg * 8) = v;
  }
}

// ---------------- K3: conv via 9 shifted MFMA-GEMMs, dbuf global_load_lds ----
__launch_bounds__(256)
__global__ void k_conv(const unsigned short* __restrict__ xt,
                       const unsigned short* __restrict__ wA,
                       const float* __restrict__ noise,
                       const float* __restrict__ nw,
                       float* __restrict__ out) {
  // two linear buffers, 1536 uint4 each (1296 used + slack), 49152 B total
  __shared__ uint4 ldsraw[2][1536];
  int b = blockIdx.y;
  int tile = blockIdx.x;
  int th = (tile >> 3) * 16, tw = (tile & 7) * 16;
  int t = threadIdx.x;
  int lane = t & 63, wv = t >> 6;
  int wm = wv >> 1, wn = wv & 1;
  int lc = lane & 15, lg = lane >> 4;

  f32x4 acc[4][8];
#pragma unroll
  for (int mi = 0; mi < 4; ++mi)
#pragma unroll
    for (int j = 0; j < 8; ++j) acc[mi][j] = (f32x4){0.f, 0.f, 0.f, 0.f};

  const unsigned short* xtile = xt + ((size_t)b * 130 + th) * 130 * CIN + (size_t)tw * CIN;
  const unsigned short* wbase = wA + (size_t)b * 9 * COUT * CIN
                                + (size_t)(wm * 64 + lc) * CIN + lg * 8;

  // precompute per-thread staging source offsets (elements) for 6 load slots
  int goff[6];
#pragma unroll
  for (int i = 0; i < 6; ++i) {
    int idx = i * 256 + t;
    int cell = idx >> 2, g = idx & 3;
    int y = cell / 18, xx = cell - y * 18;
    goff[i] = (y * 130 + xx) * CIN + g * 8;
  }
  int ldsslot = wv * 64; // uint4 units; lane offset is implicit in global_load_lds

  // stage chunk q into buffer bb
  auto STAGE = [&](int bb, int q) {
    const unsigned short* xq = xtile + q * 32;
#pragma unroll
    for (int i = 0; i < 6; ++i) {
      int idx = i * 256 + t;
      if (idx < 1296)
        gl_lds16(xq + goff[i], &ldsraw[bb][i * 256 + ldsslot]);
    }
  };

  STAGE(0, 0);
  __syncthreads();

  for (int q = 0; q < 4; ++q) {
    if (q < 3) STAGE((q + 1) & 1, q + 1); // issue next-chunk loads BEFORE compute
    const unsigned short* bb_lds = (const unsigned short*)&ldsraw[q & 1][0];
    const unsigned short* wq = wbase + (size_t)q * 32;
#pragma unroll
    for (int ky = 0; ky < 3; ++ky) {
#pragma unroll
      for (int kx = 0; kx < 3; ++kx) {
        int tap = ky * 3 + kx;
        bf16x8 af[4];
#pragma unroll
        for (int mi = 0; mi < 4; ++mi)
          af[mi] = *(const bf16x8*)(wq + ((size_t)tap * COUT + mi * 16) * CIN);
#pragma unroll
        for (int j = 0; j < 8; ++j) {
          int unit = ((wn * 8 + j + ky) * 18 + (lc + kx)) * 4 + lg;
          bf16x8 bv = *(const bf16x8*)(bb_lds + (size_t)unit * 8);
#pragma unroll
          for (int mi = 0; mi < 4; ++mi)
            acc[mi][j] = __builtin_amdgcn_mfma_f32_16x16x32_bf16(af[mi], bv, acc[mi][j], 0, 0, 0);
        }
      }
    }
    __syncthreads(); // drains vmcnt(0): next buffer ready; loads had whole compute to land
  }

  // ---- epilogue ----
  float nwv[4][4];
#pragma unroll
  for (int mi = 0; mi < 4; ++mi)
#pragma unroll
    for (int r = 0; r < 4; ++r) nwv[mi][r] = nw[wm * 64 + mi * 16 + lg * 4 + r];
#pragma unroll
  for (int j = 0; j < 8; ++j) {
    int hh = th + wn * 8 + j, ww = tw + lc;
    float nv = noise[((size_t)b * HH + hh) * WW + ww];
#pragma unroll
    for (int mi = 0; mi < 4; ++mi) {
      int cobase = wm * 64 + mi * 16 + lg * 4;
#pragma unroll
      for (int r = 0; r < 4; ++r)
        out[(((size_t)b * COUT + cobase + r) * HH + hh) * WW + ww] = acc[mi][j][r] + nwv[mi][r] * nv;
    }
  }
}

extern "C" void kernel_launch(void* const* d_in, const int* in_sizes, int n_in,
                              void* d_out, int out_size, void* d_ws, size_t ws_size,
                              hipStream_t stream) {
  const float* x      = (const float*)d_in[0];
  const float* style  = (const float*)d_in[1];
  const float* noise  = (const float*)d_in[2];
  const float* weight = (const float*)d_in[3];
  const float* mod_w  = (const float*)d_in[4];
  const float* nw     = (const float*)d_in[5];
  float* out = (float*)d_out;
  char* ws = (char*)d_ws;
  if (ws_size < WS_NEEDED) return;

  float* s = (float*)ws;
  unsigned short* wA = (unsigned short*)(ws + WA_OFF);
  unsigned short* xt = (unsigned short*)(ws + XT_OFF);

  k_style<<<dim3(NB), dim3(CIN), 0, stream>>>(style, mod_w, s);
  k_wprep<<<dim3(COUT, NB), dim3(CIN), 0, stream>>>(weight, s, wA);
  k_xt<<<dim3(130, NB), dim3(256), 0, stream>>>(x, xt);
  k_conv<<<dim3(64, NB), dim3(256), 0, stream>>>(xt, wA, noise, nw, out);
}